// Round 1
// 2466.071 us; speedup vs baseline: 1.1404x; 1.1404x over previous
//
#include <hip/hip_runtime.h>

// Problem constants (B,S,F,L) = (512, 1024, 64, 128)
constexpr int Bn = 512;
constexpr int Sn = 1024;
constexpr int Fn = 64;
constexpr int Ln = 128;
constexpr int Gn = 4 * Ln;  // 512 gate rows (i,f,g,o)

typedef unsigned int u32;
typedef _Float16 h2 __attribute__((ext_vector_type(2)));

// ---- cross-lane helpers ----
template <int CTRL>
__device__ __forceinline__ float dpp_add(float v) {
  int s = __builtin_amdgcn_mov_dpp(__float_as_int(v), CTRL, 0xF, 0xF, true);
  return v + __int_as_float(s);
}
// 0xB1 = quad_perm(1,0,3,2) = xor1; 0x4E = quad_perm(2,3,0,1) = xor2

__device__ __forceinline__ float fdot2(u32 a, u32 b, float c) {
  return __builtin_amdgcn_fdot2(__builtin_bit_cast(h2, a), __builtin_bit_cast(h2, b), c, false);
}

__device__ __forceinline__ float fsig(float v) {
  return __builtin_amdgcn_rcpf(1.0f + __expf(-v));
}
__device__ __forceinline__ float ftanh(float v) {
  return 2.0f * __builtin_amdgcn_rcpf(1.0f + __expf(-2.0f * v)) - 1.0f;
}

// Pack encoder weights + dense weights to fp16 in workspace.
__global__ void pack_kernel(const float* __restrict__ Wih, const float* __restrict__ Whh,
                            const float* __restrict__ Wd,
                            _Float16* __restrict__ WhE, _Float16* __restrict__ WxE,
                            _Float16* __restrict__ WdH) {
  const int i = blockIdx.x * 256 + threadIdx.x;  // grid covers 65536
  if (i < Gn * Ln) WhE[i] = (_Float16)Whh[i];
  if (i < Gn * Fn) WxE[i] = (_Float16)Wih[i];
  if (i < Fn * Ln) WdH[i] = (_Float16)Wd[i];
}

// Fold decoder dense into the recurrence (fp32 math, fp16 result):
//   W_comb[t,l] = W_hh_dec[t,l] + sum_j W_ih_dec[t,j] * W_dense[j,l]
//   b_comb[t]   = b_ih_dec[t] + b_hh_dec[t] + sum_j W_ih_dec[t,j] * b_dense[j]
__global__ void combine_dec_kernel(const float* __restrict__ Wih, const float* __restrict__ Whh,
                                   const float* __restrict__ bih, const float* __restrict__ bhh,
                                   const float* __restrict__ Wd, const float* __restrict__ bd,
                                   _Float16* __restrict__ WcH, float* __restrict__ bc) {
  const int t = blockIdx.x;   // gate row 0..511
  const int l = threadIdx.x;  // latent col 0..127
  float s = Whh[t * Ln + l];
#pragma unroll
  for (int j = 0; j < Fn; ++j) s += Wih[t * Fn + j] * Wd[j * Ln + l];
  WcH[t * Ln + l] = (_Float16)s;
  if (l == 0) {
    float sb = bih[t] + bhh[t];
#pragma unroll
    for (int j = 0; j < Fn; ++j) sb += Wih[t * Fn + j] * bd[j];
    bc[t] = sb;
  }
}

// Persistent RNN, r6 restructure: 512 blocks x 512 threads, ONE batch elem per
// block, TWO co-resident blocks per CU (16 waves/CU, 4/SIMD).
// Theory: r5 at 2 elems/block + 1 block/CU was latency-bound on the
// barrier-serialized per-step chain (post-barrier LDS latency + 24-deep fdot2
// chains + transcendental activation chain) -- with 2 lockstep waves/SIMD
// nothing hides it (measured 3400 cyc/step vs ~1240 issue cycles). Two
// INDEPENDENT blocks per CU give each SIMD 4 waves in two unsynchronized
// barrier domains, so one block's serial phase overlaps the other's dot issue.
// Per-thread weight regs are invariant (96 u32 = 512x192 halfs / 512 thr);
// per-wave per-step work halves (96 fdot2, 6 ds_read_b128, 4 accumulators).
// __launch_bounds__(512, 4): 4 waves/EU -> 2 blocks/CU, VGPR cap 128
// (budget: wh 64 + wx 32 + bias 4 + acc 4 + c + temps ~ 118).
// Thread t: q = t&3 (K-quarter), rA = t>>2 (latent 0..127). Owns gate rows
// {rA, rA+128, rA+256, rA+384} = (i,f,g,o) of latent rA -> after the 4-lane
// DPP quad all-reduce the cell update is LOCAL to lane q==0; one barrier/step.
__global__ __launch_bounds__(512, 4)
void rae_persistent_kernel(
    const float* __restrict__ x,
    const _Float16* __restrict__ WhE, const _Float16* __restrict__ WxE,
    const float* __restrict__ bih_e, const float* __restrict__ bhh_e,
    const _Float16* __restrict__ WcH, const float* __restrict__ bc,
    const _Float16* __restrict__ WdH, const float* __restrict__ bd,
    float* __restrict__ out) {
  const int t = threadIdx.x;
  const int q = t & 3;    // K-quarter: h[32q..32q+32), x[16q..16q+16)
  const int rA = t >> 2;  // latent 0..127
  const int b = blockIdx.x;

  __shared__ __align__(16) _Float16 hs[2][Ln];  // [buf][latent]
  __shared__ __align__(16) _Float16 xs[2][Fn];  // [buf][feature]

  // ---- encoder weights: 4 rows x (16 h-half2 + 8 x-half2) = 96 u32 regs ----
  u32 wh[4][16], wx[4][8];
  float bias[4];
#pragma unroll
  for (int g = 0; g < 4; ++g) {
    const int row = g * Ln + rA;
    const uint4* ph = (const uint4*)(WhE + row * Ln + q * 32);
#pragma unroll
    for (int k = 0; k < 4; ++k) {
      uint4 v = ph[k];
      wh[g][4 * k] = v.x; wh[g][4 * k + 1] = v.y; wh[g][4 * k + 2] = v.z; wh[g][4 * k + 3] = v.w;
    }
    const uint4* px = (const uint4*)(WxE + row * Fn + q * 16);
#pragma unroll
    for (int k = 0; k < 2; ++k) {
      uint4 v = px[k];
      wx[g][4 * k] = v.x; wx[g][4 * k + 1] = v.y; wx[g][4 * k + 2] = v.z; wx[g][4 * k + 3] = v.w;
    }
    bias[g] = bih_e[row] + bhh_e[row];
  }

  float c = 0.0f;  // lane q==0: cell state for latent rA

  // x staging: t<32 -> feature pair f2 = t (2 floats each, 32*2 = 64 = Fn)
  const float* xbase = x + (size_t)b * Sn * Fn + 2 * t;  // deref'd only t<32

  if (t < 64) ((u32*)&hs[0][0])[t] = 0u;  // zero h buffer 0 (128 halfs = 64 u32)
  if (t < 32) {
    float2 v = *(const float2*)xbase;
    h2 p = {(_Float16)v.x, (_Float16)v.y};
    ((u32*)&xs[0][0])[t] = __builtin_bit_cast(u32, p);
  }
  __syncthreads();

  // ================= encoder: 1024 steps =================
  for (int step = 0; step < Sn; ++step) {
    const int cur = step & 1, nx = cur ^ 1;
    float2 xv;
    const bool pf = (t < 32) && (step + 1 < Sn);
    if (pf) xv = *(const float2*)(xbase + (size_t)(step + 1) * Fn);

    float a[4];
#pragma unroll
    for (int g = 0; g < 4; ++g) a[g] = 0.0f;

    const uint4* hp = (const uint4*)&hs[cur][q * 32];
#pragma unroll
    for (int k = 0; k < 4; ++k) {
      uint4 v = hp[k];
#pragma unroll
      for (int g = 0; g < 4; ++g) {
        a[g] = fdot2(wh[g][4 * k], v.x, a[g]);
        a[g] = fdot2(wh[g][4 * k + 1], v.y, a[g]);
        a[g] = fdot2(wh[g][4 * k + 2], v.z, a[g]);
        a[g] = fdot2(wh[g][4 * k + 3], v.w, a[g]);
      }
    }
    const uint4* xp = (const uint4*)&xs[cur][q * 16];
#pragma unroll
    for (int k = 0; k < 2; ++k) {
      uint4 v = xp[k];
#pragma unroll
      for (int g = 0; g < 4; ++g) {
        a[g] = fdot2(wx[g][4 * k], v.x, a[g]);
        a[g] = fdot2(wx[g][4 * k + 1], v.y, a[g]);
        a[g] = fdot2(wx[g][4 * k + 2], v.z, a[g]);
        a[g] = fdot2(wx[g][4 * k + 3], v.w, a[g]);
      }
    }
    // quad all-reduce (DPP xor1, xor2)
#pragma unroll
    for (int g = 0; g < 4; ++g) a[g] = dpp_add<0x4E>(dpp_add<0xB1>(a[g]));

    if (q == 0) {  // local cell update for latent rA
      float gi = fsig(a[0] + bias[0]);
      float gf = fsig(a[1] + bias[1]);
      float gg = ftanh(a[2] + bias[2]);
      float go = fsig(a[3] + bias[3]);
      c = gf * c + gi * gg;
      hs[nx][rA] = (_Float16)(go * ftanh(c));
    }
    if (pf) {
      h2 p = {(_Float16)xv.x, (_Float16)xv.y};
      ((u32*)&xs[nx][0])[t] = __builtin_bit_cast(u32, p);
    }
    __syncthreads();
  }

  // ================= decoder: 1024 steps =================
#pragma unroll
  for (int g = 0; g < 4; ++g) {  // reload wh with folded W_comb (fp16)
    const int row = g * Ln + rA;
    const uint4* pc = (const uint4*)(WcH + row * Ln + q * 32);
#pragma unroll
    for (int k = 0; k < 4; ++k) {
      uint4 v = pc[k];
      wh[g][4 * k] = v.x; wh[g][4 * k + 1] = v.y; wh[g][4 * k + 2] = v.z; wh[g][4 * k + 3] = v.w;
    }
    bias[g] = bc[row];
  }
  // dense epilogue: waves 0-3 only (t<256, wave-uniform branch); a quad
  // covers the K-quarters of output feature oj.
  const int oj = (t >> 2) & 63;
  u32 dw[16];
  float dbias = 0.0f;
  if (t < 256) {
    const uint4* pd = (const uint4*)(WdH + oj * Ln + q * 32);
#pragma unroll
    for (int k = 0; k < 4; ++k) {
      uint4 v = pd[k];
      dw[4 * k] = v.x; dw[4 * k + 1] = v.y; dw[4 * k + 2] = v.z; dw[4 * k + 3] = v.w;
    }
    dbias = bd[oj];
  }
  float* op = out + (size_t)b * Sn * Fn + (size_t)(Sn - 1) * Fn + oj;

  for (int step = 0; step < Sn; ++step) {
    const int cur = step & 1, nx = cur ^ 1;
    float a[4];
#pragma unroll
    for (int g = 0; g < 4; ++g) a[g] = 0.0f;

    const uint4* hp = (const uint4*)&hs[cur][q * 32];
#pragma unroll
    for (int k = 0; k < 4; ++k) {
      uint4 v = hp[k];
#pragma unroll
      for (int g = 0; g < 4; ++g) {
        a[g] = fdot2(wh[g][4 * k], v.x, a[g]);
        a[g] = fdot2(wh[g][4 * k + 1], v.y, a[g]);
        a[g] = fdot2(wh[g][4 * k + 2], v.z, a[g]);
        a[g] = fdot2(wh[g][4 * k + 3], v.w, a[g]);
      }
    }
#pragma unroll
    for (int g = 0; g < 4; ++g) a[g] = dpp_add<0x4E>(dpp_add<0xB1>(a[g]));

    if (q == 0) {
      float gi = fsig(a[0] + bias[0]);
      float gf = fsig(a[1] + bias[1]);
      float gg = ftanh(a[2] + bias[2]);
      float go = fsig(a[3] + bias[3]);
      c = gf * c + gi * gg;
      hs[nx][rA] = (_Float16)(go * ftanh(c));
    }
    __syncthreads();

    // dense epilogue on just-written h (buffer nx): out[b, S-1-step, oj].
    // Reads hs[nx]; a fast wave's next-iteration writes go to hs[cur] -> no
    // barrier needed between dense and the next step's dots.
    if (t < 256) {
      const uint4* he = (const uint4*)&hs[nx][q * 32];
      float d = 0.0f;
#pragma unroll
      for (int k = 0; k < 4; ++k) {
        uint4 v = he[k];
        d = fdot2(dw[4 * k], v.x, d);
        d = fdot2(dw[4 * k + 1], v.y, d);
        d = fdot2(dw[4 * k + 2], v.z, d);
        d = fdot2(dw[4 * k + 3], v.w, d);
      }
      d = dpp_add<0x4E>(dpp_add<0xB1>(d));
      if (q == 0) op[0] = d + dbias;
    }
    op -= Fn;
  }
}

extern "C" void kernel_launch(void* const* d_in, const int* in_sizes, int n_in,
                              void* d_out, int out_size, void* d_ws, size_t ws_size,
                              hipStream_t stream) {
  const float* x     = (const float*)d_in[0];
  const float* Wih_e = (const float*)d_in[1];
  const float* Whh_e = (const float*)d_in[2];
  const float* bih_e = (const float*)d_in[3];
  const float* bhh_e = (const float*)d_in[4];
  const float* Wih_d = (const float*)d_in[5];
  const float* Whh_d = (const float*)d_in[6];
  const float* bih_d = (const float*)d_in[7];
  const float* bhh_d = (const float*)d_in[8];
  const float* Wd    = (const float*)d_in[9];
  const float* bd    = (const float*)d_in[10];
  float* out = (float*)d_out;

  // workspace layout (fp16 weight copies + fp32 combined bias)
  _Float16* WhE = (_Float16*)d_ws;           // 512*128
  _Float16* WxE = WhE + Gn * Ln;             // 512*64
  _Float16* WcH = WxE + Gn * Fn;             // 512*128
  _Float16* WdH = WcH + Gn * Ln;             // 64*128
  float* bc = (float*)(WdH + Fn * Ln);       // 512

  pack_kernel<<<256, 256, 0, stream>>>(Wih_e, Whh_e, Wd, WhE, WxE, WdH);
  combine_dec_kernel<<<Gn, Ln, 0, stream>>>(Wih_d, Whh_d, bih_d, bhh_d, Wd, bd, WcH, bc);
  rae_persistent_kernel<<<Bn, 512, 0, stream>>>(x, WhE, WxE, bih_e, bhh_e,
                                                WcH, bc, WdH, bd, out);
}

// Round 4
// 2317.767 us; speedup vs baseline: 1.2134x; 1.0640x over previous
//
#include <hip/hip_runtime.h>

// Problem constants (B,S,F,L) = (512, 1024, 64, 128)
constexpr int Bn = 512;
constexpr int Sn = 1024;
constexpr int Fn = 64;
constexpr int Ln = 128;
constexpr int Gn = 4 * Ln;  // 512 gate rows (i,f,g,o)

typedef unsigned int u32;
typedef _Float16 h2 __attribute__((ext_vector_type(2)));
typedef _Float16 h8 __attribute__((ext_vector_type(8)));
typedef float f4 __attribute__((ext_vector_type(4)));

// ---- cross-lane helpers ----
template <int CTRL>
__device__ __forceinline__ float dpp_mov(float v) {
  return __int_as_float(__builtin_amdgcn_mov_dpp(__float_as_int(v), CTRL, 0xF, 0xF, true));
}
template <int CTRL>
__device__ __forceinline__ float dpp_add(float v) {
  return v + dpp_mov<CTRL>(v);
}
// 0xB1 = quad_perm(1,0,3,2) = xor1; 0x4E = quad_perm(2,3,0,1) = xor2

__device__ __forceinline__ float fdot2(u32 a, u32 b, float c) {
  return __builtin_amdgcn_fdot2(__builtin_bit_cast(h2, a), __builtin_bit_cast(h2, b), c, false);
}

__device__ __forceinline__ float fsig(float v) {
  return __builtin_amdgcn_rcpf(1.0f + __expf(-v));
}

// Pack encoder weights + dense weights to fp16 in workspace.
__global__ void pack_kernel(const float* __restrict__ Wih, const float* __restrict__ Whh,
                            const float* __restrict__ Wd,
                            _Float16* __restrict__ WhE, _Float16* __restrict__ WxE,
                            _Float16* __restrict__ WdH) {
  const int i = blockIdx.x * 256 + threadIdx.x;  // grid covers 65536
  if (i < Gn * Ln) WhE[i] = (_Float16)Whh[i];
  if (i < Gn * Fn) WxE[i] = (_Float16)Wih[i];
  if (i < Fn * Ln) WdH[i] = (_Float16)Wd[i];
}

// Fold decoder dense into the recurrence (fp32 math, fp16 result).
__global__ void combine_dec_kernel(const float* __restrict__ Wih, const float* __restrict__ Whh,
                                   const float* __restrict__ bih, const float* __restrict__ bhh,
                                   const float* __restrict__ Wd, const float* __restrict__ bd,
                                   _Float16* __restrict__ WcH, float* __restrict__ bc) {
  const int t = blockIdx.x;   // gate row 0..511
  const int l = threadIdx.x;  // latent col 0..127
  float s = Whh[t * Ln + l];
#pragma unroll
  for (int j = 0; j < Fn; ++j) s += Wih[t * Fn + j] * Wd[j * Ln + l];
  WcH[t * Ln + l] = (_Float16)s;
  if (l == 0) {
    float sb = bih[t] + bhh[t];
#pragma unroll
    for (int j = 0; j < Fn; ++j) sb += Wih[t * Fn + j] * bd[j];
    bc[t] = sb;
  }
}

// Encoder input projection prepass: pre[b*S+s][perm(col)] = x[b,s,:] @ W_ih^T[col] + b_enc[col]
// perm(col) = (col&127)*4 + (col>>7)  <=>  thread t (q=t&3, rA=t>>2) reads slot t for its
// gate row q*128+rA. MFMA fp16 16x16x32, fp32 accumulate/store. M=524288, N=512, K=64.
// Correctness argument: A and B use the same per-lane K-ordering (contiguous kb*8+j), and any
// consistent K-permutation cancels between the operands; C layout col=lane&15,
// row=(lane>>4)*4+reg is the m89-verified one (dtype-independent on gfx950).
__global__ __launch_bounds__(256)
void xw_gemm_kernel(const float* __restrict__ x, const _Float16* __restrict__ WxE,
                    const float* __restrict__ bih, const float* __restrict__ bhh,
                    float* __restrict__ pre) {
  // W staged as [n=512][k=64] halfs with row stride 36 u32 (144B: 16B-aligned, bank-spread)
  __shared__ u32 wl[512 * 36];
  const int tid = threadIdx.x;
  const uint4* wsrc = (const uint4*)WxE;  // 4096 uint4
#pragma unroll
  for (int it = 0; it < 16; ++it) {
    int i = tid + it * 256;
    int n = i >> 3, k4 = i & 7;
    uint4 v = wsrc[i];
    *(uint4*)&wl[n * 36 + k4 * 4] = v;
  }
  __syncthreads();

  const int w = tid >> 6, lane = tid & 63;
  const int m = lane & 15, kb = lane >> 4;
  const long row = (long)blockIdx.x * 64 + w * 16 + m;
  const float* ap = x + row * 64 + kb * 8;
  h8 A0, A1;
  {
    float4 f0 = *(const float4*)(ap);
    float4 f1 = *(const float4*)(ap + 4);
    float4 f2 = *(const float4*)(ap + 32);
    float4 f3 = *(const float4*)(ap + 36);
    A0[0]=(_Float16)f0.x; A0[1]=(_Float16)f0.y; A0[2]=(_Float16)f0.z; A0[3]=(_Float16)f0.w;
    A0[4]=(_Float16)f1.x; A0[5]=(_Float16)f1.y; A0[6]=(_Float16)f1.z; A0[7]=(_Float16)f1.w;
    A1[0]=(_Float16)f2.x; A1[1]=(_Float16)f2.y; A1[2]=(_Float16)f2.z; A1[3]=(_Float16)f2.w;
    A1[4]=(_Float16)f3.x; A1[5]=(_Float16)f3.y; A1[6]=(_Float16)f3.z; A1[7]=(_Float16)f3.w;
  }
  const long rbase = (long)blockIdx.x * 64 + w * 16 + kb * 4;
#pragma unroll 4
  for (int nt = 0; nt < 32; ++nt) {
    int n = nt * 16 + m;
    h8 B0 = *(const h8*)&wl[n * 36 + kb * 4];       // k = kb*8..kb*8+8
    h8 B1 = *(const h8*)&wl[n * 36 + 16 + kb * 4];  // k = 32+kb*8..
    f4 acc = {0.f, 0.f, 0.f, 0.f};
    acc = __builtin_amdgcn_mfma_f32_16x16x32_f16(A0, B0, acc, 0, 0, 0);
    acc = __builtin_amdgcn_mfma_f32_16x16x32_f16(A1, B1, acc, 0, 0, 0);
    int col = n;  // C col = lane&15 = m
    float bsum = bih[col] + bhh[col];
    int perm = ((col & 127) << 2) | (col >> 7);
#pragma unroll
    for (int rr = 0; rr < 4; ++rr)
      pre[(rbase + rr) * 512 + perm] = acc[rr] + bsum;
  }
}

// Persistent RNN, r9 (= r8 minus the stray unassignable no-op line that broke
// compilation): 512 blocks x 512 threads, 1 elem/block, 2 blocks/CU.
// Quarter-K dot structure (4 ds_read_b128 + 64 fdot2/wave/step) + two
// derivation-checked improvements over round-1:
//  - lane-parallel activation: after the DPP quad all-reduce every lane holds
//    all 4 gate sums a[0..3]; lane q selects a[q] (3 cndmasks), applies ONE
//    transcendental (tanh for q==2 via ms/bs), then a 2-DPP combine puts c,h
//    in lane q==1. Replaces the exec-masked 10-transcendental serial tail.
//  - PRE: encoder x@W_ih^T + b_enc precomputed by xw_gemm_kernel; persistent
//    kernel reads 1 coalesced dword/thread/step (slot t = its gate row).
// Thread t: q = t&3 (K-quarter), rA = t>>2 (latent). Lane owns quarter q of
// gate rows {rA, rA+128, rA+256, rA+384}; post-reduce it consumes gate row
// q*128+rA. One barrier per step.
template <bool PRE>
__global__ __launch_bounds__(512, 4)
void rae_persistent_kernel(
    const float* __restrict__ x, const float* __restrict__ pre,
    const _Float16* __restrict__ WhE, const _Float16* __restrict__ WxE,
    const float* __restrict__ bih_e, const float* __restrict__ bhh_e,
    const _Float16* __restrict__ WcH, const float* __restrict__ bc,
    const _Float16* __restrict__ WdH, const float* __restrict__ bd,
    float* __restrict__ out) {
  const int t = threadIdx.x;
  const int q = t & 3;    // K-quarter: h[32q..32q+32), x[16q..16q+16)
  const int rA = t >> 2;  // latent 0..127
  const int b = blockIdx.x;
  const int rsel = q * 128 + rA;  // gate row this lane consumes post-reduce

  __shared__ __align__(16) _Float16 hs[2][Ln];
  __shared__ __align__(16) _Float16 xs[2][Fn];  // fallback only

  // per-lane activation constants: lane q==2 (cell gate) computes tanh
  const float ms = (q == 2) ? 2.0f : 1.0f;
  const float bs = (q == 2) ? -1.0f : 0.0f;

  // ---- encoder weights: 4 gate rows x quarter-K = 64 u32 ----
  u32 wh[4][16];
#pragma unroll
  for (int g = 0; g < 4; ++g) {
    const int row = g * Ln + rA;
    const uint4* ph = (const uint4*)(WhE + row * Ln + q * 32);
#pragma unroll
    for (int k = 0; k < 4; ++k) {
      uint4 v = ph[k];
      wh[g][4 * k] = v.x; wh[g][4 * k + 1] = v.y; wh[g][4 * k + 2] = v.z; wh[g][4 * k + 3] = v.w;
    }
  }
  u32 wx[4][8];
  float biasl = 0.0f;
  if constexpr (!PRE) {
#pragma unroll
    for (int g = 0; g < 4; ++g) {
      const int row = g * Ln + rA;
      const uint4* px = (const uint4*)(WxE + row * Fn + q * 16);
#pragma unroll
      for (int k = 0; k < 2; ++k) {
        uint4 v = px[k];
        wx[g][4 * k] = v.x; wx[g][4 * k + 1] = v.y; wx[g][4 * k + 2] = v.z; wx[g][4 * k + 3] = v.w;
      }
    }
    biasl = bih_e[rsel] + bhh_e[rsel];
  }

  float c = 0.0f;  // valid in lane q==1 only (garbage elsewhere, never read)

  const float* xbase = x + (size_t)b * Sn * Fn + 2 * t;  // deref'd only t<32 (fallback)
  const float* pbase = pre + (size_t)b * Sn * 512 + t;
  float pv = 0.0f;
  if constexpr (PRE) pv = pbase[0];

  if (t < 64) ((u32*)&hs[0][0])[t] = 0u;  // zero h buffer 0
  if constexpr (!PRE) {
    if (t < 32) {
      float2 v = *(const float2*)xbase;
      h2 p = {(_Float16)v.x, (_Float16)v.y};
      ((u32*)&xs[0][0])[t] = __builtin_bit_cast(u32, p);
    }
  }
  __syncthreads();

  // ================= encoder: 1024 steps =================
  for (int step = 0; step < Sn; ++step) {
    const int cur = step & 1, nx = cur ^ 1;
    const bool last = (step + 1 == Sn);
    float pnext = 0.0f;
    float2 xv;
    if constexpr (PRE) {
      if (!last) pnext = pbase[(size_t)(step + 1) * 512];
    } else {
      if (t < 32 && !last) xv = *(const float2*)(xbase + (size_t)(step + 1) * Fn);
    }

    float a[4];
#pragma unroll
    for (int g = 0; g < 4; ++g) a[g] = 0.0f;

    const uint4* hp = (const uint4*)&hs[cur][q * 32];
#pragma unroll
    for (int k = 0; k < 4; ++k) {
      uint4 v = hp[k];
#pragma unroll
      for (int g = 0; g < 4; ++g) {
        a[g] = fdot2(wh[g][4 * k], v.x, a[g]);
        a[g] = fdot2(wh[g][4 * k + 1], v.y, a[g]);
        a[g] = fdot2(wh[g][4 * k + 2], v.z, a[g]);
        a[g] = fdot2(wh[g][4 * k + 3], v.w, a[g]);
      }
    }
    if constexpr (!PRE) {
      const uint4* xp = (const uint4*)&xs[cur][q * 16];
#pragma unroll
      for (int k = 0; k < 2; ++k) {
        uint4 v = xp[k];
#pragma unroll
        for (int g = 0; g < 4; ++g) {
          a[g] = fdot2(wx[g][4 * k], v.x, a[g]);
          a[g] = fdot2(wx[g][4 * k + 1], v.y, a[g]);
          a[g] = fdot2(wx[g][4 * k + 2], v.z, a[g]);
          a[g] = fdot2(wx[g][4 * k + 3], v.w, a[g]);
        }
      }
    }
    // quad all-reduce (DPP xor1, xor2): all 4 lanes end with all 4 gate sums
#pragma unroll
    for (int g = 0; g < 4; ++g) a[g] = dpp_add<0x4E>(dpp_add<0xB1>(a[g]));

    __builtin_amdgcn_s_setprio(1);  // serial tail: win arbitration vs other block
    // lane q selects gate q (constant indices only -> 3 cndmasks, no scratch)
    float lo = (q & 1) ? a[1] : a[0];
    float hi = (q & 1) ? a[3] : a[2];
    float pa = ((q & 2) ? hi : lo) + (PRE ? pv : biasl);
    // lane-parallel activation: act = ms*sigmoid(ms*pa)+bs  (q==2 -> tanh(pa))
    float act = __builtin_fmaf(ms, fsig(ms * pa), bs);
    // quad combine: lane1 (f) owns c,h
    float v2 = dpp_mov<0x4E>(act);   // lane0:g~ lane1:o lane2:i lane3:f
    float prod = act * v2;           // lane0: i*g~
    float pc = dpp_mov<0xB1>(prod);  // lane1 <- i*g~
    c = __builtin_fmaf(act, c, pc);  // lane1: f*c + i*g~
    float tc = __builtin_fmaf(2.0f, fsig(2.0f * c), -1.0f);  // tanh(c)
    float hval = v2 * tc;            // lane1: o*tanh(c)
    if (q == 1) hs[nx][rA] = (_Float16)hval;
    __builtin_amdgcn_s_setprio(0);

    if constexpr (PRE) {
      pv = pnext;
    } else {
      if (t < 32 && !last) {
        h2 p = {(_Float16)xv.x, (_Float16)xv.y};
        ((u32*)&xs[nx][0])[t] = __builtin_bit_cast(u32, p);
      }
    }
    __syncthreads();
  }

  // ================= decoder: 1024 steps =================
#pragma unroll
  for (int g = 0; g < 4; ++g) {  // reload wh with folded W_comb (fp16)
    const int row = g * Ln + rA;
    const uint4* pc4 = (const uint4*)(WcH + row * Ln + q * 32);
#pragma unroll
    for (int k = 0; k < 4; ++k) {
      uint4 v = pc4[k];
      wh[g][4 * k] = v.x; wh[g][4 * k + 1] = v.y; wh[g][4 * k + 2] = v.z; wh[g][4 * k + 3] = v.w;
    }
  }
  const float biasd = bc[rsel];
  // dense epilogue: oj = t>>3 (0..63 output feature), k8 = t&7 (K-eighth)
  const int oj = t >> 3, k8 = t & 7;
  u32 dw[8];
  {
    const uint4* pd = (const uint4*)(WdH + oj * Ln + k8 * 16);
#pragma unroll
    for (int k = 0; k < 2; ++k) {
      uint4 v = pd[k];
      dw[4 * k] = v.x; dw[4 * k + 1] = v.y; dw[4 * k + 2] = v.z; dw[4 * k + 3] = v.w;
    }
  }
  const float dbias = bd[oj];
  float* op = out + (size_t)b * Sn * Fn + (size_t)(Sn - 1) * Fn + oj;

  for (int step = 0; step < Sn; ++step) {
    const int cur = step & 1, nx = cur ^ 1;
    float a[4];
#pragma unroll
    for (int g = 0; g < 4; ++g) a[g] = 0.0f;

    const uint4* hp = (const uint4*)&hs[cur][q * 32];
#pragma unroll
    for (int k = 0; k < 4; ++k) {
      uint4 v = hp[k];
#pragma unroll
      for (int g = 0; g < 4; ++g) {
        a[g] = fdot2(wh[g][4 * k], v.x, a[g]);
        a[g] = fdot2(wh[g][4 * k + 1], v.y, a[g]);
        a[g] = fdot2(wh[g][4 * k + 2], v.z, a[g]);
        a[g] = fdot2(wh[g][4 * k + 3], v.w, a[g]);
      }
    }
#pragma unroll
    for (int g = 0; g < 4; ++g) a[g] = dpp_add<0x4E>(dpp_add<0xB1>(a[g]));

    __builtin_amdgcn_s_setprio(1);
    float lo = (q & 1) ? a[1] : a[0];
    float hi = (q & 1) ? a[3] : a[2];
    float pa = ((q & 2) ? hi : lo) + biasd;
    float act = __builtin_fmaf(ms, fsig(ms * pa), bs);
    float v2 = dpp_mov<0x4E>(act);
    float prod = act * v2;
    float pc = dpp_mov<0xB1>(prod);
    c = __builtin_fmaf(act, c, pc);
    float tc = __builtin_fmaf(2.0f, fsig(2.0f * c), -1.0f);
    float hval = v2 * tc;
    if (q == 1) hs[nx][rA] = (_Float16)hval;
    __builtin_amdgcn_s_setprio(0);
    __syncthreads();

    // dense on just-written h (buffer nx): out[b, S-1-step, oj].
    // Safe without a second barrier: next iter's h-write targets the other
    // buffer, and barrier skew is bounded to <1 iteration.
    const uint4* he = (const uint4*)&hs[nx][k8 * 16];
    float d = 0.0f;
    {
      uint4 v = he[0];
      d = fdot2(dw[0], v.x, d); d = fdot2(dw[1], v.y, d);
      d = fdot2(dw[2], v.z, d); d = fdot2(dw[3], v.w, d);
      v = he[1];
      d = fdot2(dw[4], v.x, d); d = fdot2(dw[5], v.y, d);
      d = fdot2(dw[6], v.z, d); d = fdot2(dw[7], v.w, d);
    }
    // 8-lane reduce: xor1, xor2 (DPP) + xor4 (ds_swizzle)
    d = dpp_add<0xB1>(d);
    d = dpp_add<0x4E>(d);
    d += __int_as_float(__builtin_amdgcn_ds_swizzle(__float_as_int(d), 0x101F));
    if (k8 == 0) op[0] = d + dbias;
    op -= Fn;
  }
}

extern "C" void kernel_launch(void* const* d_in, const int* in_sizes, int n_in,
                              void* d_out, int out_size, void* d_ws, size_t ws_size,
                              hipStream_t stream) {
  const float* x     = (const float*)d_in[0];
  const float* Wih_e = (const float*)d_in[1];
  const float* Whh_e = (const float*)d_in[2];
  const float* bih_e = (const float*)d_in[3];
  const float* bhh_e = (const float*)d_in[4];
  const float* Wih_d = (const float*)d_in[5];
  const float* Whh_d = (const float*)d_in[6];
  const float* bih_d = (const float*)d_in[7];
  const float* bhh_d = (const float*)d_in[8];
  const float* Wd    = (const float*)d_in[9];
  const float* bd    = (const float*)d_in[10];
  float* out = (float*)d_out;

  // workspace layout (fp16 weight copies + fp32 combined bias [+ fp32 pre])
  _Float16* WhE = (_Float16*)d_ws;           // 512*128
  _Float16* WxE = WhE + Gn * Ln;             // 512*64
  _Float16* WcH = WxE + Gn * Fn;             // 512*128
  _Float16* WdH = WcH + Gn * Ln;             // 64*128
  float* bc = (float*)(WdH + Fn * Ln);       // 512
  const size_t fixed_bytes = (size_t)(Gn * Ln + Gn * Fn + Gn * Ln + Fn * Ln) * 2 + Gn * 4;
  const size_t pre_off = (fixed_bytes + 255) & ~(size_t)255;
  const size_t pre_bytes = (size_t)Bn * Sn * 512 * 4;  // 1.074 GB
  float* pre = (float*)((char*)d_ws + pre_off);
  const bool use_pre = ws_size >= pre_off + pre_bytes;

  pack_kernel<<<256, 256, 0, stream>>>(Wih_e, Whh_e, Wd, WhE, WxE, WdH);
  combine_dec_kernel<<<Gn, Ln, 0, stream>>>(Wih_d, Whh_d, bih_d, bhh_d, Wd, bd, WcH, bc);
  if (use_pre) {
    xw_gemm_kernel<<<(Bn * Sn) / 64, 256, 0, stream>>>(x, WxE, bih_e, bhh_e, pre);
    rae_persistent_kernel<true><<<Bn, 512, 0, stream>>>(x, pre, WhE, WxE, bih_e, bhh_e,
                                                        WcH, bc, WdH, bd, out);
  } else {
    rae_persistent_kernel<false><<<Bn, 512, 0, stream>>>(x, pre, WhE, WxE, bih_e, bhh_e,
                                                         WcH, bc, WdH, bd, out);
  }
}

// Round 5
// 2302.160 us; speedup vs baseline: 1.2216x; 1.0068x over previous
//
#include <hip/hip_runtime.h>

// Problem constants (B,S,F,L) = (512, 1024, 64, 128)
constexpr int Bn = 512;
constexpr int Sn = 1024;
constexpr int Fn = 64;
constexpr int Ln = 128;
constexpr int Gn = 4 * Ln;  // 512 gate rows (i,f,g,o)

typedef unsigned int u32;
typedef _Float16 h2 __attribute__((ext_vector_type(2)));
typedef _Float16 h8 __attribute__((ext_vector_type(8)));
typedef float f4 __attribute__((ext_vector_type(4)));

// ---- cross-lane helpers ----
template <int CTRL>
__device__ __forceinline__ float dpp_mov(float v) {
  return __int_as_float(__builtin_amdgcn_mov_dpp(__float_as_int(v), CTRL, 0xF, 0xF, true));
}
template <int CTRL>
__device__ __forceinline__ float dpp_add(float v) {
  return v + dpp_mov<CTRL>(v);
}
// 0xB1 = quad_perm(1,0,3,2) = xor1; 0x4E = quad_perm(2,3,0,1) = xor2
__device__ __forceinline__ float swz_xor4(float v) {  // lane ^ 4
  return __int_as_float(__builtin_amdgcn_ds_swizzle(__float_as_int(v), 0x101F));
}
__device__ __forceinline__ float swz_xor8(float v) {  // lane ^ 8
  return __int_as_float(__builtin_amdgcn_ds_swizzle(__float_as_int(v), 0x201F));
}

__device__ __forceinline__ float fdot2(u32 a, u32 b, float c) {
  return __builtin_amdgcn_fdot2(__builtin_bit_cast(h2, a), __builtin_bit_cast(h2, b), c, false);
}

__device__ __forceinline__ float fsig(float v) {
  return __builtin_amdgcn_rcpf(1.0f + __expf(-v));
}

// Pack encoder weights + dense weights to fp16 in workspace.
__global__ void pack_kernel(const float* __restrict__ Wih, const float* __restrict__ Whh,
                            const float* __restrict__ Wd,
                            _Float16* __restrict__ WhE, _Float16* __restrict__ WxE,
                            _Float16* __restrict__ WdH) {
  const int i = blockIdx.x * 256 + threadIdx.x;  // grid covers 65536
  if (i < Gn * Ln) WhE[i] = (_Float16)Whh[i];
  if (i < Gn * Fn) WxE[i] = (_Float16)Wih[i];
  if (i < Fn * Ln) WdH[i] = (_Float16)Wd[i];
}

// Fold decoder dense into the recurrence (fp32 math, fp16 result).
__global__ void combine_dec_kernel(const float* __restrict__ Wih, const float* __restrict__ Whh,
                                   const float* __restrict__ bih, const float* __restrict__ bhh,
                                   const float* __restrict__ Wd, const float* __restrict__ bd,
                                   _Float16* __restrict__ WcH, float* __restrict__ bc) {
  const int t = blockIdx.x;   // gate row 0..511
  const int l = threadIdx.x;  // latent col 0..127
  float s = Whh[t * Ln + l];
#pragma unroll
  for (int j = 0; j < Fn; ++j) s += Wih[t * Fn + j] * Wd[j * Ln + l];
  WcH[t * Ln + l] = (_Float16)s;
  if (l == 0) {
    float sb = bih[t] + bhh[t];
#pragma unroll
    for (int j = 0; j < Fn; ++j) sb += Wih[t * Fn + j] * bd[j];
    bc[t] = sb;
  }
}

// Encoder input projection prepass, fp16 output (537 MB vs r4's 1.07 GB fp32,
// which did NOT fit the workspace -> the PRE path never ran in r4):
//   preH[b*S+s][slot(col)] = fp16( x[b,s,:] @ W_ih^T[col] + b_enc[col] )
// slot(col) = (col&127)*4 + (col>>7) = rA*4 + gate. fp16 pre rounds the exact
// fp32 product once -- numerically BETTER than the fallback (x and W both
// rounded to fp16 before the dot). MFMA fp16 16x16x32; C layout col=lane&15,
// row=(lane>>4)*4+reg (m89-verified); any consistent K-permutation cancels
// between A and B operands.
__global__ __launch_bounds__(256)
void xw_gemm_kernel(const float* __restrict__ x, const _Float16* __restrict__ WxE,
                    const float* __restrict__ bih, const float* __restrict__ bhh,
                    _Float16* __restrict__ preH) {
  // W staged as [n=512][k=64] halfs with row stride 36 u32 (144B: 16B-aligned, bank-spread)
  __shared__ u32 wl[512 * 36];
  const int tid = threadIdx.x;
  const uint4* wsrc = (const uint4*)WxE;  // 4096 uint4
#pragma unroll
  for (int it = 0; it < 16; ++it) {
    int i = tid + it * 256;
    int n = i >> 3, k4 = i & 7;
    uint4 v = wsrc[i];
    *(uint4*)&wl[n * 36 + k4 * 4] = v;
  }
  __syncthreads();

  const int w = tid >> 6, lane = tid & 63;
  const int m = lane & 15, kb = lane >> 4;
  const long row = (long)blockIdx.x * 64 + w * 16 + m;
  const float* ap = x + row * 64 + kb * 8;
  h8 A0, A1;
  {
    float4 f0 = *(const float4*)(ap);
    float4 f1 = *(const float4*)(ap + 4);
    float4 f2 = *(const float4*)(ap + 32);
    float4 f3 = *(const float4*)(ap + 36);
    A0[0]=(_Float16)f0.x; A0[1]=(_Float16)f0.y; A0[2]=(_Float16)f0.z; A0[3]=(_Float16)f0.w;
    A0[4]=(_Float16)f1.x; A0[5]=(_Float16)f1.y; A0[6]=(_Float16)f1.z; A0[7]=(_Float16)f1.w;
    A1[0]=(_Float16)f2.x; A1[1]=(_Float16)f2.y; A1[2]=(_Float16)f2.z; A1[3]=(_Float16)f2.w;
    A1[4]=(_Float16)f3.x; A1[5]=(_Float16)f3.y; A1[6]=(_Float16)f3.z; A1[7]=(_Float16)f3.w;
  }
  const long rbase = (long)blockIdx.x * 64 + w * 16 + kb * 4;
#pragma unroll 4
  for (int nt = 0; nt < 32; ++nt) {
    int n = nt * 16 + m;
    h8 B0 = *(const h8*)&wl[n * 36 + kb * 4];       // k = kb*8..kb*8+8
    h8 B1 = *(const h8*)&wl[n * 36 + 16 + kb * 4];  // k = 32+kb*8..
    f4 acc = {0.f, 0.f, 0.f, 0.f};
    acc = __builtin_amdgcn_mfma_f32_16x16x32_f16(A0, B0, acc, 0, 0, 0);
    acc = __builtin_amdgcn_mfma_f32_16x16x32_f16(A1, B1, acc, 0, 0, 0);
    int col = n;  // C col = lane&15 = m
    float bsum = bih[col] + bhh[col];
    int perm = ((col & 127) << 2) | (col >> 7);
#pragma unroll
    for (int rr = 0; rr < 4; ++rr)
      preH[(rbase + rr) * 512 + perm] = (_Float16)(acc[rr] + bsum);
  }
}

// r10 PRE kernel: 512 blocks x 1024 threads (2048 thr/CU = 100% occupancy,
// 8 waves/SIMD, two independent barrier domains per CU).
// r4 was VALU-throughput-bound (VALUBusy 80%, issue model closes at 2880
// cyc/step); this halves per-thread VALU work by doubling threads/elem:
// thread t: q = t&3 (K-quarter), g2 = (t>>2)&1 (gate pair), rA = t>>3.
// Dots: 2 gate rows {2g2, 2g2+1} x quarter-K = 32 fdot2 (was 96).
// Quad all-reduce (bits 0-1) -> all 4 lanes hold both pair sums; lane selects
// gate = 2*g2 + (t&1). Gates live on lane bits {0,2}: i=(0,0) f=(1,0)
// g~=(0,1) o=(1,1). Cell combine (per-lane derivation):
//   v2 = swz^4(act)  : i<->g~, f<->o   (bit-2 partner)
//   prod = act*v2    : at i-lane = i*g~
//   pc = qperm^1(prod): f-lane <- i*g~ (bit-0 partner)
//   c = fma(act,c,pc): f-lane: f*c + i*g~
//   h = v2 * tanh(c) : f-lane: o*tanh(c)
// Writer = f-lane with (t&2)==0 -> (t&7)==1; bit1 lanes are pure duplicates
// post-reduce. __launch_bounds__(1024,8) caps VGPR at 64 (budget ~55).
__global__ __launch_bounds__(1024, 8)
void rae_pre_kernel(const _Float16* __restrict__ preH,
                    const _Float16* __restrict__ WhE,
                    const _Float16* __restrict__ WcH, const float* __restrict__ bc,
                    const _Float16* __restrict__ WdH, const float* __restrict__ bd,
                    float* __restrict__ out) {
  const int t = threadIdx.x;
  const int q = t & 3;          // K-quarter: h[32q..32q+32)
  const int g2 = (t >> 2) & 1;  // gate pair
  const int b0 = t & 1;         // gate low bit (post-select)
  const int rA = t >> 3;        // latent 0..127
  const int b = blockIdx.x;
  const int gate = 2 * g2 + b0;
  const int r0 = (2 * g2) * Ln + rA;
  const int r1 = (2 * g2 + 1) * Ln + rA;

  __shared__ __align__(16) _Float16 hs[2][Ln];

  // lane with gate==2 (cell gate) computes tanh via ms/bs
  const float ms = (gate == 2) ? 2.0f : 1.0f;
  const float bs = (gate == 2) ? -1.0f : 0.0f;

  // ---- encoder weights: 2 gate rows x quarter-K = 32 u32 ----
  u32 w0[16], w1[16];
  {
    const uint4* p0 = (const uint4*)(WhE + (size_t)r0 * Ln + q * 32);
    const uint4* p1 = (const uint4*)(WhE + (size_t)r1 * Ln + q * 32);
#pragma unroll
    for (int k = 0; k < 4; ++k) {
      uint4 v = p0[k];
      w0[4 * k] = v.x; w0[4 * k + 1] = v.y; w0[4 * k + 2] = v.z; w0[4 * k + 3] = v.w;
      uint4 u = p1[k];
      w1[4 * k] = u.x; w1[4 * k + 1] = u.y; w1[4 * k + 2] = u.z; w1[4 * k + 3] = u.w;
    }
  }

  float c = 0.0f;  // valid only in f-lanes (b0==1, g2==0); garbage elsewhere

  // pre slot for this lane's gate row: rA*4 + gate (b1-duplicates share it)
  const _Float16* pbase = preH + (size_t)b * Sn * 512 + (rA * 4 + gate);
  float pv = (float)pbase[0];

  if (t < 64) ((u32*)&hs[0][0])[t] = 0u;  // zero h buffer 0
  __syncthreads();

  // ================= encoder: 1024 steps =================
  for (int step = 0; step < Sn; ++step) {
    const int cur = step & 1, nx = cur ^ 1;
    float pnext = 0.0f;
    if (step + 1 < Sn) pnext = (float)pbase[(size_t)(step + 1) * 512];

    float a0 = 0.0f, a1 = 0.0f;
    const uint4* hp = (const uint4*)&hs[cur][q * 32];
#pragma unroll
    for (int k = 0; k < 4; ++k) {
      uint4 v = hp[k];
      a0 = fdot2(w0[4 * k], v.x, a0);
      a0 = fdot2(w0[4 * k + 1], v.y, a0);
      a0 = fdot2(w0[4 * k + 2], v.z, a0);
      a0 = fdot2(w0[4 * k + 3], v.w, a0);
      a1 = fdot2(w1[4 * k], v.x, a1);
      a1 = fdot2(w1[4 * k + 1], v.y, a1);
      a1 = fdot2(w1[4 * k + 2], v.z, a1);
      a1 = fdot2(w1[4 * k + 3], v.w, a1);
    }
    // quad all-reduce (bits 0-1): every lane gets both full pair sums
    a0 = dpp_add<0x4E>(dpp_add<0xB1>(a0));
    a1 = dpp_add<0x4E>(dpp_add<0xB1>(a1));

    __builtin_amdgcn_s_setprio(1);
    float pa = (b0 ? a1 : a0) + pv;  // pv includes b_enc
    float act = __builtin_fmaf(ms, fsig(ms * pa), bs);
    float v2 = swz_xor4(act);        // bit-2 partner: i<->g~, f<->o
    float prod = act * v2;           // i-lane: i*g~
    float pc = dpp_mov<0xB1>(prod);  // f-lane <- i*g~
    c = __builtin_fmaf(act, c, pc);  // f-lane: f*c + i*g~
    float tc = __builtin_fmaf(2.0f, fsig(2.0f * c), -1.0f);  // tanh(c)
    float hval = v2 * tc;            // f-lane: o*tanh(c)
    if ((t & 7) == 1) hs[nx][rA] = (_Float16)hval;
    __builtin_amdgcn_s_setprio(0);

    pv = pnext;
    __syncthreads();
  }

  // ================= decoder: 1024 steps =================
  {
    const uint4* p0 = (const uint4*)(WcH + (size_t)r0 * Ln + q * 32);
    const uint4* p1 = (const uint4*)(WcH + (size_t)r1 * Ln + q * 32);
#pragma unroll
    for (int k = 0; k < 4; ++k) {
      uint4 v = p0[k];
      w0[4 * k] = v.x; w0[4 * k + 1] = v.y; w0[4 * k + 2] = v.z; w0[4 * k + 3] = v.w;
      uint4 u = p1[k];
      w1[4 * k] = u.x; w1[4 * k + 1] = u.y; w1[4 * k + 2] = u.z; w1[4 * k + 3] = u.w;
    }
  }
  const float biasd = bc[gate * Ln + rA];
  // dense epilogue: oj = t>>4 (output feature), k16 = t&15 (K-sixteenth)
  const int oj = t >> 4, k16 = t & 15;
  u32 dw[4];
  {
    uint4 v = *(const uint4*)(WdH + oj * Ln + k16 * 8);
    dw[0] = v.x; dw[1] = v.y; dw[2] = v.z; dw[3] = v.w;
  }
  const float dbias = bd[oj];
  float* op = out + (size_t)b * Sn * Fn + (size_t)(Sn - 1) * Fn + oj;

  for (int step = 0; step < Sn; ++step) {
    const int cur = step & 1, nx = cur ^ 1;
    float a0 = 0.0f, a1 = 0.0f;
    const uint4* hp = (const uint4*)&hs[cur][q * 32];
#pragma unroll
    for (int k = 0; k < 4; ++k) {
      uint4 v = hp[k];
      a0 = fdot2(w0[4 * k], v.x, a0);
      a0 = fdot2(w0[4 * k + 1], v.y, a0);
      a0 = fdot2(w0[4 * k + 2], v.z, a0);
      a0 = fdot2(w0[4 * k + 3], v.w, a0);
      a1 = fdot2(w1[4 * k], v.x, a1);
      a1 = fdot2(w1[4 * k + 1], v.y, a1);
      a1 = fdot2(w1[4 * k + 2], v.z, a1);
      a1 = fdot2(w1[4 * k + 3], v.w, a1);
    }
    a0 = dpp_add<0x4E>(dpp_add<0xB1>(a0));
    a1 = dpp_add<0x4E>(dpp_add<0xB1>(a1));

    __builtin_amdgcn_s_setprio(1);
    float pa = (b0 ? a1 : a0) + biasd;
    float act = __builtin_fmaf(ms, fsig(ms * pa), bs);
    float v2 = swz_xor4(act);
    float prod = act * v2;
    float pc = dpp_mov<0xB1>(prod);
    c = __builtin_fmaf(act, c, pc);
    float tc = __builtin_fmaf(2.0f, fsig(2.0f * c), -1.0f);
    float hval = v2 * tc;
    if ((t & 7) == 1) hs[nx][rA] = (_Float16)hval;
    __builtin_amdgcn_s_setprio(0);
    __syncthreads();

    // dense on just-written h (buffer nx): out[b, S-1-step, oj].
    // Next iter's h-write targets the other buffer; skew <1 barrier.
    float d = 0.0f;
    {
      uint4 v = *(const uint4*)&hs[nx][k16 * 8];
      d = fdot2(dw[0], v.x, d); d = fdot2(dw[1], v.y, d);
      d = fdot2(dw[2], v.z, d); d = fdot2(dw[3], v.w, d);
    }
    // 16-lane reduce: xor1, xor2 (DPP) + xor4, xor8 (ds_swizzle)
    d = dpp_add<0xB1>(d);
    d = dpp_add<0x4E>(d);
    d += swz_xor4(d);
    d += swz_xor8(d);
    if (k16 == 0) op[0] = d + dbias;
    op -= Fn;
  }
}

// ==== r9 fallback (verified, 2460 us): used when ws can't hold fp16 pre ====
template <bool PRE>
__global__ __launch_bounds__(512, 4)
void rae_persistent_kernel(
    const float* __restrict__ x, const float* __restrict__ pre,
    const _Float16* __restrict__ WhE, const _Float16* __restrict__ WxE,
    const float* __restrict__ bih_e, const float* __restrict__ bhh_e,
    const _Float16* __restrict__ WcH, const float* __restrict__ bc,
    const _Float16* __restrict__ WdH, const float* __restrict__ bd,
    float* __restrict__ out) {
  const int t = threadIdx.x;
  const int q = t & 3;
  const int rA = t >> 2;
  const int b = blockIdx.x;
  const int rsel = q * 128 + rA;

  __shared__ __align__(16) _Float16 hs[2][Ln];
  __shared__ __align__(16) _Float16 xs[2][Fn];

  const float ms = (q == 2) ? 2.0f : 1.0f;
  const float bs = (q == 2) ? -1.0f : 0.0f;

  u32 wh[4][16];
#pragma unroll
  for (int g = 0; g < 4; ++g) {
    const int row = g * Ln + rA;
    const uint4* ph = (const uint4*)(WhE + row * Ln + q * 32);
#pragma unroll
    for (int k = 0; k < 4; ++k) {
      uint4 v = ph[k];
      wh[g][4 * k] = v.x; wh[g][4 * k + 1] = v.y; wh[g][4 * k + 2] = v.z; wh[g][4 * k + 3] = v.w;
    }
  }
  u32 wx[4][8];
  float biasl = 0.0f;
  if constexpr (!PRE) {
#pragma unroll
    for (int g = 0; g < 4; ++g) {
      const int row = g * Ln + rA;
      const uint4* px = (const uint4*)(WxE + row * Fn + q * 16);
#pragma unroll
      for (int k = 0; k < 2; ++k) {
        uint4 v = px[k];
        wx[g][4 * k] = v.x; wx[g][4 * k + 1] = v.y; wx[g][4 * k + 2] = v.z; wx[g][4 * k + 3] = v.w;
      }
    }
    biasl = bih_e[rsel] + bhh_e[rsel];
  }

  float c = 0.0f;

  const float* xbase = x + (size_t)b * Sn * Fn + 2 * t;
  const float* pbase = pre + (size_t)b * Sn * 512 + t;
  float pv = 0.0f;
  if constexpr (PRE) pv = pbase[0];

  if (t < 64) ((u32*)&hs[0][0])[t] = 0u;
  if constexpr (!PRE) {
    if (t < 32) {
      float2 v = *(const float2*)xbase;
      h2 p = {(_Float16)v.x, (_Float16)v.y};
      ((u32*)&xs[0][0])[t] = __builtin_bit_cast(u32, p);
    }
  }
  __syncthreads();

  for (int step = 0; step < Sn; ++step) {
    const int cur = step & 1, nx = cur ^ 1;
    const bool last = (step + 1 == Sn);
    float pnext = 0.0f;
    float2 xv;
    if constexpr (PRE) {
      if (!last) pnext = pbase[(size_t)(step + 1) * 512];
    } else {
      if (t < 32 && !last) xv = *(const float2*)(xbase + (size_t)(step + 1) * Fn);
    }

    float a[4];
#pragma unroll
    for (int g = 0; g < 4; ++g) a[g] = 0.0f;

    const uint4* hp = (const uint4*)&hs[cur][q * 32];
#pragma unroll
    for (int k = 0; k < 4; ++k) {
      uint4 v = hp[k];
#pragma unroll
      for (int g = 0; g < 4; ++g) {
        a[g] = fdot2(wh[g][4 * k], v.x, a[g]);
        a[g] = fdot2(wh[g][4 * k + 1], v.y, a[g]);
        a[g] = fdot2(wh[g][4 * k + 2], v.z, a[g]);
        a[g] = fdot2(wh[g][4 * k + 3], v.w, a[g]);
      }
    }
    if constexpr (!PRE) {
      const uint4* xp = (const uint4*)&xs[cur][q * 16];
#pragma unroll
      for (int k = 0; k < 2; ++k) {
        uint4 v = xp[k];
#pragma unroll
        for (int g = 0; g < 4; ++g) {
          a[g] = fdot2(wx[g][4 * k], v.x, a[g]);
          a[g] = fdot2(wx[g][4 * k + 1], v.y, a[g]);
          a[g] = fdot2(wx[g][4 * k + 2], v.z, a[g]);
          a[g] = fdot2(wx[g][4 * k + 3], v.w, a[g]);
        }
      }
    }
#pragma unroll
    for (int g = 0; g < 4; ++g) a[g] = dpp_add<0x4E>(dpp_add<0xB1>(a[g]));

    __builtin_amdgcn_s_setprio(1);
    float lo = (q & 1) ? a[1] : a[0];
    float hi = (q & 1) ? a[3] : a[2];
    float pa = ((q & 2) ? hi : lo) + (PRE ? pv : biasl);
    float act = __builtin_fmaf(ms, fsig(ms * pa), bs);
    float v2 = dpp_mov<0x4E>(act);
    float prod = act * v2;
    float pc = dpp_mov<0xB1>(prod);
    c = __builtin_fmaf(act, c, pc);
    float tc = __builtin_fmaf(2.0f, fsig(2.0f * c), -1.0f);
    float hval = v2 * tc;
    if (q == 1) hs[nx][rA] = (_Float16)hval;
    __builtin_amdgcn_s_setprio(0);

    if constexpr (PRE) {
      pv = pnext;
    } else {
      if (t < 32 && !last) {
        h2 p = {(_Float16)xv.x, (_Float16)xv.y};
        ((u32*)&xs[nx][0])[t] = __builtin_bit_cast(u32, p);
      }
    }
    __syncthreads();
  }

#pragma unroll
  for (int g = 0; g < 4; ++g) {
    const int row = g * Ln + rA;
    const uint4* pc4 = (const uint4*)(WcH + row * Ln + q * 32);
#pragma unroll
    for (int k = 0; k < 4; ++k) {
      uint4 v = pc4[k];
      wh[g][4 * k] = v.x; wh[g][4 * k + 1] = v.y; wh[g][4 * k + 2] = v.z; wh[g][4 * k + 3] = v.w;
    }
  }
  const float biasd = bc[rsel];
  const int oj = t >> 3, k8 = t & 7;
  u32 dw[8];
  {
    const uint4* pd = (const uint4*)(WdH + oj * Ln + k8 * 16);
#pragma unroll
    for (int k = 0; k < 2; ++k) {
      uint4 v = pd[k];
      dw[4 * k] = v.x; dw[4 * k + 1] = v.y; dw[4 * k + 2] = v.z; dw[4 * k + 3] = v.w;
    }
  }
  const float dbias = bd[oj];
  float* op = out + (size_t)b * Sn * Fn + (size_t)(Sn - 1) * Fn + oj;

  for (int step = 0; step < Sn; ++step) {
    const int cur = step & 1, nx = cur ^ 1;
    float a[4];
#pragma unroll
    for (int g = 0; g < 4; ++g) a[g] = 0.0f;

    const uint4* hp = (const uint4*)&hs[cur][q * 32];
#pragma unroll
    for (int k = 0; k < 4; ++k) {
      uint4 v = hp[k];
#pragma unroll
      for (int g = 0; g < 4; ++g) {
        a[g] = fdot2(wh[g][4 * k], v.x, a[g]);
        a[g] = fdot2(wh[g][4 * k + 1], v.y, a[g]);
        a[g] = fdot2(wh[g][4 * k + 2], v.z, a[g]);
        a[g] = fdot2(wh[g][4 * k + 3], v.w, a[g]);
      }
    }
#pragma unroll
    for (int g = 0; g < 4; ++g) a[g] = dpp_add<0x4E>(dpp_add<0xB1>(a[g]));

    __builtin_amdgcn_s_setprio(1);
    float lo = (q & 1) ? a[1] : a[0];
    float hi = (q & 1) ? a[3] : a[2];
    float pa = ((q & 2) ? hi : lo) + biasd;
    float act = __builtin_fmaf(ms, fsig(ms * pa), bs);
    float v2 = dpp_mov<0x4E>(act);
    float prod = act * v2;
    float pc = dpp_mov<0xB1>(prod);
    c = __builtin_fmaf(act, c, pc);
    float tc = __builtin_fmaf(2.0f, fsig(2.0f * c), -1.0f);
    float hval = v2 * tc;
    if (q == 1) hs[nx][rA] = (_Float16)hval;
    __builtin_amdgcn_s_setprio(0);
    __syncthreads();

    const uint4* he = (const uint4*)&hs[nx][k8 * 16];
    float d = 0.0f;
    {
      uint4 v = he[0];
      d = fdot2(dw[0], v.x, d); d = fdot2(dw[1], v.y, d);
      d = fdot2(dw[2], v.z, d); d = fdot2(dw[3], v.w, d);
      v = he[1];
      d = fdot2(dw[4], v.x, d); d = fdot2(dw[5], v.y, d);
      d = fdot2(dw[6], v.z, d); d = fdot2(dw[7], v.w, d);
    }
    d = dpp_add<0xB1>(d);
    d = dpp_add<0x4E>(d);
    d += swz_xor4(d);
    if (k8 == 0) op[0] = d + dbias;
    op -= Fn;
  }
}

extern "C" void kernel_launch(void* const* d_in, const int* in_sizes, int n_in,
                              void* d_out, int out_size, void* d_ws, size_t ws_size,
                              hipStream_t stream) {
  const float* x     = (const float*)d_in[0];
  const float* Wih_e = (const float*)d_in[1];
  const float* Whh_e = (const float*)d_in[2];
  const float* bih_e = (const float*)d_in[3];
  const float* bhh_e = (const float*)d_in[4];
  const float* Wih_d = (const float*)d_in[5];
  const float* Whh_d = (const float*)d_in[6];
  const float* bih_d = (const float*)d_in[7];
  const float* bhh_d = (const float*)d_in[8];
  const float* Wd    = (const float*)d_in[9];
  const float* bd    = (const float*)d_in[10];
  float* out = (float*)d_out;

  // workspace layout (fp16 weight copies + fp32 combined bias [+ fp16 pre])
  _Float16* WhE = (_Float16*)d_ws;           // 512*128
  _Float16* WxE = WhE + Gn * Ln;             // 512*64
  _Float16* WcH = WxE + Gn * Fn;             // 512*128
  _Float16* WdH = WcH + Gn * Ln;             // 64*128
  float* bc = (float*)(WdH + Fn * Ln);       // 512
  const size_t fixed_bytes = (size_t)(Gn * Ln + Gn * Fn + Gn * Ln + Fn * Ln) * 2 + Gn * 4;
  const size_t pre_off = (fixed_bytes + 255) & ~(size_t)255;
  const size_t pre_bytes = (size_t)Bn * Sn * 512 * 2;  // 537 MB fp16
  _Float16* preH = (_Float16*)((char*)d_ws + pre_off);
  const bool use_pre = ws_size >= pre_off + pre_bytes;

  pack_kernel<<<256, 256, 0, stream>>>(Wih_e, Whh_e, Wd, WhE, WxE, WdH);
  combine_dec_kernel<<<Gn, Ln, 0, stream>>>(Wih_d, Whh_d, bih_d, bhh_d, Wd, bd, WcH, bc);
  if (use_pre) {
    xw_gemm_kernel<<<(Bn * Sn) / 64, 256, 0, stream>>>(x, WxE, bih_e, bhh_e, preH);
    rae_pre_kernel<<<Bn, 1024, 0, stream>>>(preH, WhE, WcH, bc, WdH, bd, out);
  } else {
    rae_persistent_kernel<false><<<Bn, 512, 0, stream>>>(x, nullptr, WhE, WxE, bih_e, bhh_e,
                                                         WcH, bc, WdH, bd, out);
  }
}

// Round 6
// 1820.170 us; speedup vs baseline: 1.5451x; 1.2648x over previous
//
#include <hip/hip_runtime.h>

// Problem constants (B,S,F,L) = (512, 1024, 64, 128)
constexpr int Bn = 512;
constexpr int Sn = 1024;
constexpr int Fn = 64;
constexpr int Ln = 128;
constexpr int Gn = 4 * Ln;  // 512 gate rows (i,f,g,o)
constexpr int CH = 32;      // encoder pre-chunk: steps per in-kernel x-GEMM
constexpr int NCH = Sn / CH;

typedef unsigned int u32;
typedef _Float16 h2 __attribute__((ext_vector_type(2)));
typedef _Float16 h8 __attribute__((ext_vector_type(8)));
typedef float f4 __attribute__((ext_vector_type(4)));

// ---- cross-lane helpers (dense epilogue reduce) ----
template <int CTRL>
__device__ __forceinline__ float dpp_mov(float v) {
  return __int_as_float(__builtin_amdgcn_mov_dpp(__float_as_int(v), CTRL, 0xF, 0xF, true));
}
template <int CTRL>
__device__ __forceinline__ float dpp_add(float v) {
  return v + dpp_mov<CTRL>(v);
}
// 0xB1 = quad_perm xor1; 0x4E = quad_perm xor2
__device__ __forceinline__ float swz_xor4(float v) {  // lane ^ 4
  return __int_as_float(__builtin_amdgcn_ds_swizzle(__float_as_int(v), 0x101F));
}

__device__ __forceinline__ float fdot2(u32 a, u32 b, float c) {
  return __builtin_amdgcn_fdot2(__builtin_bit_cast(h2, a), __builtin_bit_cast(h2, b), c, false);
}
__device__ __forceinline__ float fsig(float v) {
  return __builtin_amdgcn_rcpf(1.0f + __expf(-v));
}
__device__ __forceinline__ h8 as_h8(uint4 v) { return __builtin_bit_cast(h8, v); }

// Pack encoder weights + dense weights to fp16 in workspace.
__global__ void pack_kernel(const float* __restrict__ Wih, const float* __restrict__ Whh,
                            const float* __restrict__ Wd,
                            _Float16* __restrict__ WhE, _Float16* __restrict__ WxE,
                            _Float16* __restrict__ WdH) {
  const int i = blockIdx.x * 256 + threadIdx.x;  // grid covers 65536
  if (i < Gn * Ln) WhE[i] = (_Float16)Whh[i];
  if (i < Gn * Fn) WxE[i] = (_Float16)Wih[i];
  if (i < Fn * Ln) WdH[i] = (_Float16)Wd[i];
}

// Fold decoder dense into the recurrence (fp32 math, fp16 result).
__global__ void combine_dec_kernel(const float* __restrict__ Wih, const float* __restrict__ Whh,
                                   const float* __restrict__ bih, const float* __restrict__ bhh,
                                   const float* __restrict__ Wd, const float* __restrict__ bd,
                                   _Float16* __restrict__ WcH, float* __restrict__ bc) {
  const int t = blockIdx.x;   // gate row 0..511
  const int l = threadIdx.x;  // latent col 0..127
  float s = Whh[t * Ln + l];
#pragma unroll
  for (int j = 0; j < Fn; ++j) s += Wih[t * Fn + j] * Wd[j * Ln + l];
  WcH[t * Ln + l] = (_Float16)s;
  if (l == 0) {
    float sb = bih[t] + bhh[t];
#pragma unroll
    for (int j = 0; j < Fn; ++j) sb += Wih[t * Fn + j] * bd[j];
    bc[t] = sb;
  }
}

// r11 MFMA persistent kernel. 512 blocks x 512 thr (8 waves), 2 blocks/CU.
// RATIONALE (r5 counters): VALU-bound at 83% busy doing a GEMM recurrence on
// fdot2 (73 TF = 23% of vector ceiling) while MfmaUtil=0; and r9's 96 weight
// u32/thread vs VGPR_Count=64 implies AGPR copy traffic in the loop.
//
// Per step: gates[1x512] = h[1x128] @ W^T via mfma_f32_16x16x32_f16.
//  - A-frag (M=1 broadcast): every lane loads the same 16B h-slice
//    hs[kt*32 + (l>>4)*8 ..+8) -> all 16 A rows equal h; C rows are then all
//    identical (no garbage/NaN anywhere). 4 broadcast ds_read_b128.
//  - B-frag: lane l holds B[k=(l>>4)*8+j'][col=l&15] = W[tile*16+(l&15)][k]
//    -> 16B contiguous row slice of WhE; 16 uint4, loop-invariant in VGPRs.
//  - Wave w owns N-tiles {w, w+8, w+16, w+24} = i/f/g~/o blocks of latents
//    w*16..w*16+15 -> acc0..acc3[0] at lane l<16 are THE 4 gate sums of
//    latent w*16+l: cell update is lane-local (c in lanes 0..15/wave).
//    (All lane groups compute identical copies; only l<16 writes h.)
// Encoder x-projection: in-kernel chunked MFMA prepass every CH=32 steps:
//  pre[32x512] (fp32 LDS, 64KB) = x_chunk[32x64] @ Wx^T + b_enc, M=32 -> full
//  matrix-core utilization, ~0.5 MFMA/step amortized; bias folded into acc
//  init. x staged fp32->fp16 into xraw (144B row stride: 2-way banks).
// Decoder: same loop minus pre (W_comb in same regs, bias from bc) + r9's
// verified dense epilogue (oj=t>>3, k8=t&7, xor1/2/4 reduce).
__global__ __launch_bounds__(512, 4)
void rae_mfma_kernel(const float* __restrict__ x,
                     const _Float16* __restrict__ WhE, const _Float16* __restrict__ WxE,
                     const float* __restrict__ bih_e, const float* __restrict__ bhh_e,
                     const _Float16* __restrict__ WcH, const float* __restrict__ bc,
                     const _Float16* __restrict__ WdH, const float* __restrict__ bd,
                     float* __restrict__ out) {
  const int t = threadIdx.x;
  const int w = t >> 6;    // wave 0..7
  const int l = t & 63;    // lane
  const int jj = l & 15;   // tile column
  const int g16 = l >> 4;  // K-slice group (A/B frag k = g16*8..g16*8+8)
  const int b = blockIdx.x;

  __shared__ float pre[CH * 512];        // 64 KB: x@Wx^T + b for current chunk
  __shared__ u32 xraw[CH * 36];          // 32 rows x 72 halfs (144B stride)
  __shared__ __align__(16) _Float16 hs[2][Ln];

  // ---- encoder B-frags: bh[g][kt], g=gate tile, kt=K-tile ----
  uint4 bh[4][4];
#pragma unroll
  for (int g = 0; g < 4; ++g) {
    const size_t row = (size_t)((w + 8 * g) * 16 + jj);
#pragma unroll
    for (int kt = 0; kt < 4; ++kt)
      bh[g][kt] = *(const uint4*)(WhE + row * 128 + kt * 32 + g16 * 8);
  }
  float be[4];  // encoder bias for this lane's gate column (used by chunk GEMM)
#pragma unroll
  for (int g = 0; g < 4; ++g) {
    const int row = (w + 8 * g) * 16 + jj;
    be[g] = bih_e[row] + bhh_e[row];
  }

  float c = 0.0f;  // cell state for latent w*16+jj (valid lanes l<16; other
                   // lane groups hold identical copies by construction)

  if (t < 64) ((u32*)&hs[0][0])[t] = 0u;  // zero h buffer 0
  const float* xb = x + (size_t)b * Sn * Fn;

  // ================= encoder: 32 chunks x 32 steps =================
  int s = 0;
  for (int ch = 0; ch < NCH; ++ch) {
    // ---- stage x chunk fp32->fp16 into xraw (coalesced float4) ----
    {
      const int st = t >> 4, f0 = (t & 15) * 4;
      float4 v = *(const float4*)(xb + (size_t)(ch * CH + st) * Fn + f0);
      h2 p0 = {(_Float16)v.x, (_Float16)v.y};
      h2 p1 = {(_Float16)v.z, (_Float16)v.w};
      xraw[st * 36 + (t & 15) * 2] = __builtin_bit_cast(u32, p0);
      xraw[st * 36 + (t & 15) * 2 + 1] = __builtin_bit_cast(u32, p1);
    }
    __syncthreads();
    // ---- chunk GEMM: pre[st][gate] = x_st . Wx[gate] + be ----
    {
      uint4 bx[4][2];
#pragma unroll
      for (int g = 0; g < 4; ++g) {
        const size_t row = (size_t)((w + 8 * g) * 16 + jj);
#pragma unroll
        for (int kt = 0; kt < 2; ++kt)
          bx[g][kt] = *(const uint4*)(WxE + row * 64 + kt * 32 + g16 * 8);
      }
#pragma unroll
      for (int mt = 0; mt < CH / 16; ++mt) {  // 2 M-tiles of 16 steps
        h8 a0 = as_h8(*(const uint4*)&xraw[(mt * 16 + jj) * 36 + g16 * 4]);
        h8 a1 = as_h8(*(const uint4*)&xraw[(mt * 16 + jj) * 36 + 16 + g16 * 4]);
#pragma unroll
        for (int g = 0; g < 4; ++g) {
          f4 acc = {be[g], be[g], be[g], be[g]};
          acc = __builtin_amdgcn_mfma_f32_16x16x32_f16(a0, as_h8(bx[g][0]), acc, 0, 0, 0);
          acc = __builtin_amdgcn_mfma_f32_16x16x32_f16(a1, as_h8(bx[g][1]), acc, 0, 0, 0);
          const int col = (w + 8 * g) * 16 + jj;
#pragma unroll
          for (int r = 0; r < 4; ++r)
            pre[(mt * 16 + g16 * 4 + r) * 512 + col] = acc[r];
        }
      }
    }
    __syncthreads();
    // ---- 32 recurrence steps ----
    for (int ss = 0; ss < CH; ++ss, ++s) {
      const int cur = s & 1, nx = cur ^ 1;
      const uint4* hp = (const uint4*)&hs[cur][0];
      f4 a0 = {0.f, 0.f, 0.f, 0.f}, a1 = a0, a2 = a0, a3 = a0;
#pragma unroll
      for (int kt = 0; kt < 4; ++kt) {
        h8 af = as_h8(hp[kt * 4 + g16]);  // broadcast: A rows all = h
        a0 = __builtin_amdgcn_mfma_f32_16x16x32_f16(af, as_h8(bh[0][kt]), a0, 0, 0, 0);
        a1 = __builtin_amdgcn_mfma_f32_16x16x32_f16(af, as_h8(bh[1][kt]), a1, 0, 0, 0);
        a2 = __builtin_amdgcn_mfma_f32_16x16x32_f16(af, as_h8(bh[2][kt]), a2, 0, 0, 0);
        a3 = __builtin_amdgcn_mfma_f32_16x16x32_f16(af, as_h8(bh[3][kt]), a3, 0, 0, 0);
      }
      const float p0 = pre[ss * 512 + (w + 0) * 16 + jj];
      const float p1 = pre[ss * 512 + (w + 8) * 16 + jj];
      const float p2 = pre[ss * 512 + (w + 16) * 16 + jj];
      const float p3 = pre[ss * 512 + (w + 24) * 16 + jj];
      __builtin_amdgcn_s_setprio(1);
      const float gi = fsig(a0[0] + p0);
      const float gf = fsig(a1[0] + p1);
      const float gg = __builtin_fmaf(2.0f, fsig(2.0f * (a2[0] + p2)), -1.0f);  // tanh
      const float go = fsig(a3[0] + p3);
      c = __builtin_fmaf(gf, c, gi * gg);
      const float tc = __builtin_fmaf(2.0f, fsig(2.0f * c), -1.0f);
      if (l < 16) hs[nx][w * 16 + jj] = (_Float16)(go * tc);
      __builtin_amdgcn_s_setprio(0);
      __syncthreads();
    }
  }

  // ================= decoder: 1024 steps =================
#pragma unroll
  for (int g = 0; g < 4; ++g) {  // reload B-frags with folded W_comb
    const size_t row = (size_t)((w + 8 * g) * 16 + jj);
#pragma unroll
    for (int kt = 0; kt < 4; ++kt)
      bh[g][kt] = *(const uint4*)(WcH + row * 128 + kt * 32 + g16 * 8);
  }
  float bdv[4];
#pragma unroll
  for (int g = 0; g < 4; ++g) bdv[g] = bc[(w + 8 * g) * 16 + jj];

  // dense epilogue mapping (r9-verified): oj = t>>3, k8 = t&7
  const int oj = t >> 3, k8 = t & 7;
  u32 dw[8];
  {
    const uint4* pd = (const uint4*)(WdH + oj * Ln + k8 * 16);
#pragma unroll
    for (int k = 0; k < 2; ++k) {
      uint4 v = pd[k];
      dw[4 * k] = v.x; dw[4 * k + 1] = v.y; dw[4 * k + 2] = v.z; dw[4 * k + 3] = v.w;
    }
  }
  const float dbias = bd[oj];
  float* op = out + (size_t)b * Sn * Fn + (size_t)(Sn - 1) * Fn + oj;

  for (int step = 0; step < Sn; ++step) {
    const int cur = step & 1, nx = cur ^ 1;
    const uint4* hp = (const uint4*)&hs[cur][0];
    f4 a0 = {bdv[0], bdv[0], bdv[0], bdv[0]};
    f4 a1 = {bdv[1], bdv[1], bdv[1], bdv[1]};
    f4 a2 = {bdv[2], bdv[2], bdv[2], bdv[2]};
    f4 a3 = {bdv[3], bdv[3], bdv[3], bdv[3]};
#pragma unroll
    for (int kt = 0; kt < 4; ++kt) {
      h8 af = as_h8(hp[kt * 4 + g16]);
      a0 = __builtin_amdgcn_mfma_f32_16x16x32_f16(af, as_h8(bh[0][kt]), a0, 0, 0, 0);
      a1 = __builtin_amdgcn_mfma_f32_16x16x32_f16(af, as_h8(bh[1][kt]), a1, 0, 0, 0);
      a2 = __builtin_amdgcn_mfma_f32_16x16x32_f16(af, as_h8(bh[2][kt]), a2, 0, 0, 0);
      a3 = __builtin_amdgcn_mfma_f32_16x16x32_f16(af, as_h8(bh[3][kt]), a3, 0, 0, 0);
    }
    __builtin_amdgcn_s_setprio(1);
    const float gi = fsig(a0[0]);
    const float gf = fsig(a1[0]);
    const float gg = __builtin_fmaf(2.0f, fsig(2.0f * a2[0]), -1.0f);
    const float go = fsig(a3[0]);
    c = __builtin_fmaf(gf, c, gi * gg);
    const float tc = __builtin_fmaf(2.0f, fsig(2.0f * c), -1.0f);
    if (l < 16) hs[nx][w * 16 + jj] = (_Float16)(go * tc);
    __builtin_amdgcn_s_setprio(0);
    __syncthreads();

    // dense on just-written h (buffer nx): out[b, S-1-step, oj].
    // Safe: next iter's h-write targets the other buffer; skew <1 barrier.
    const uint4* he = (const uint4*)&hs[nx][k8 * 16];
    float d = 0.0f;
    {
      uint4 v = he[0];
      d = fdot2(dw[0], v.x, d); d = fdot2(dw[1], v.y, d);
      d = fdot2(dw[2], v.z, d); d = fdot2(dw[3], v.w, d);
      v = he[1];
      d = fdot2(dw[4], v.x, d); d = fdot2(dw[5], v.y, d);
      d = fdot2(dw[6], v.z, d); d = fdot2(dw[7], v.w, d);
    }
    d = dpp_add<0xB1>(d);
    d = dpp_add<0x4E>(d);
    d += swz_xor4(d);
    if (k8 == 0) op[0] = d + dbias;
    op -= Fn;
  }
}

extern "C" void kernel_launch(void* const* d_in, const int* in_sizes, int n_in,
                              void* d_out, int out_size, void* d_ws, size_t ws_size,
                              hipStream_t stream) {
  const float* x     = (const float*)d_in[0];
  const float* Wih_e = (const float*)d_in[1];
  const float* Whh_e = (const float*)d_in[2];
  const float* bih_e = (const float*)d_in[3];
  const float* bhh_e = (const float*)d_in[4];
  const float* Wih_d = (const float*)d_in[5];
  const float* Whh_d = (const float*)d_in[6];
  const float* bih_d = (const float*)d_in[7];
  const float* bhh_d = (const float*)d_in[8];
  const float* Wd    = (const float*)d_in[9];
  const float* bd    = (const float*)d_in[10];
  float* out = (float*)d_out;

  // workspace: only the fixed fp16 weight copies + combined bias (~350 KB)
  _Float16* WhE = (_Float16*)d_ws;           // 512*128
  _Float16* WxE = WhE + Gn * Ln;             // 512*64
  _Float16* WcH = WxE + Gn * Fn;             // 512*128
  _Float16* WdH = WcH + Gn * Ln;             // 64*128
  float* bc = (float*)(WdH + Fn * Ln);       // 512

  pack_kernel<<<256, 256, 0, stream>>>(Wih_e, Whh_e, Wd, WhE, WxE, WdH);
  combine_dec_kernel<<<Gn, Ln, 0, stream>>>(Wih_d, Whh_d, bih_d, bhh_d, Wd, bd, WcH, bc);
  rae_mfma_kernel<<<Bn, 512, 0, stream>>>(x, WhE, WxE, bih_e, bhh_e,
                                          WcH, bc, WdH, bd, out);
}